// Round 6
// baseline (368.691 us; speedup 1.0000x reference)
//
#include <hip/hip_runtime.h>

typedef __bf16 bf16x8 __attribute__((ext_vector_type(8)));
typedef float f32x4 __attribute__((ext_vector_type(4)));
typedef unsigned int u32x4 __attribute__((ext_vector_type(4)));
typedef unsigned short u16x4 __attribute__((ext_vector_type(4)));
typedef unsigned short u16x8 __attribute__((ext_vector_type(8)));

#define SEQ_T 4096
#define DMODEL 1024
#define HEADS 16
#define DKH 64
#define MTOK 16384  // N*T rows

#define AS1 __attribute__((address_space(1)))
#define AS3 __attribute__((address_space(3)))
#define MEMFENCE asm volatile("" ::: "memory")

__device__ __forceinline__ unsigned short f2bf(float f) {
  unsigned u = __builtin_bit_cast(unsigned int, f);
  u += 0x7FFFu + ((u >> 16) & 1u);
  return (unsigned short)(u >> 16);
}
__device__ __forceinline__ float bf2f(unsigned short h) {
  unsigned u = ((unsigned)h) << 16;
  return __builtin_bit_cast(float, u);
}
__device__ __forceinline__ void gload16(const unsigned short* g, unsigned short* l) {
  __builtin_amdgcn_global_load_lds((const AS1 unsigned int*)(g),
                                   (AS3 unsigned int*)(l), 16, 0, 0);
}

// ---------------- W (K x N) fp32 -> Wt (N x K) bf16 ----------------
__global__ void __launch_bounds__(256) k_wtrans(const float* __restrict__ W,
                                                unsigned short* __restrict__ Wt,
                                                int K, int N) {
  __shared__ float tile[32][33];
  int bn = blockIdx.x * 32, bk = blockIdx.y * 32;
  int tx = threadIdx.x, ty = threadIdx.y;  // 32 x 8
#pragma unroll
  for (int j = 0; j < 32; j += 8)
    tile[ty + j][tx] = W[(size_t)(bk + ty + j) * N + bn + tx];
  __syncthreads();
#pragma unroll
  for (int j = 0; j < 32; j += 8)
    Wt[(size_t)(bn + ty + j) * K + bk + tx] = f2bf(tile[tx][ty + j]);
}

// ====== 256x256 bf16 NT GEMM, BK=64, 8 waves (2M x 4N), 8-phase schedule =====
// C = A(MxK)*Bt(NxK)^T + bias.  AF32: A fp32, converted during reg-staging.
// Iteration = 2 K-steps: phases 0-3 consume step tA (dbuf0), 4-7 step tB
// (dbuf1).  Staging windows (buffer free-ness): dbuf1 writable at ph0-3,
// dbuf0 at ph4-7.  Rota: ph0 stage A(tB), ph1 B(tB), ph2 awrite(tB) [AF32],
// ph3 vmcnt(0) [ages 2-3 phases]; ph4 A(tA+2), ph5 B(tA+2), ph6 awrite,
// ph7 vmcnt(0).  Per phase: barrier; lgkmcnt(0); setprio1; 16 MFMA; setprio0;
// barrier.  B-frags reused across mh-phase pairs.
#define BM 256
#define BN 256
#define BK 64

template <int OBF, int SCORE, int AF32>
__global__ void __launch_bounds__(512, 2)
k_gemm(const void* __restrict__ Ain, const unsigned short* __restrict__ Bt,
       const float* __restrict__ bias, void* __restrict__ C,
       const int* __restrict__ mask, const float* __restrict__ swt,
       float* __restrict__ sbuf, int M, int N, int K) {
  __shared__ unsigned short As[2][2][128 * 64];  // [kstep parity][half][r*64+c]
  __shared__ unsigned short Bs[2][2][128 * 64];
  const int tid = threadIdx.x;
  const int lane = tid & 63, wid = tid >> 6;
  const int wr = wid >> 2, wc = wid & 3;  // 2M x 4N; per-wave C: 128 x 64
  const int l15 = lane & 15, l4 = lane >> 4;

  // bijective XCD swizzle (nwg=256, %8==0)
  const int nwg = gridDim.x * gridDim.y;
  const int flat = blockIdx.x + blockIdx.y * gridDim.x;
  const int rm = (flat & 7) * (nwg >> 3) + (flat >> 3);
  const int bx = rm % gridDim.x, by = rm / gridDim.x;
  const int bm = by * BM, bn = bx * BN;

  const float* Af = (const float*)Ain;
  const unsigned short* Abf = (const unsigned short*)Ain;
  const int nt = K / BK;

  f32x4 acc[8][4];
#pragma unroll
  for (int m = 0; m < 8; ++m)
#pragma unroll
    for (int nf = 0; nf < 4; ++nf)
#pragma unroll
      for (int e = 0; e < 4; ++e) acc[m][nf][e] = 0.f;

  // gload staging: instr covers 8 rows; lane l -> row +(l>>3), src chunk
  // (l&7)^(l>>3) (pre-swizzled); LDS linear.
  const int sgr = lane >> 3;
  const int sgc = (lane & 7) ^ sgr;
  // AF32 reg staging: rows r0+s*64, src col c8*8 (f32), swizzled write chunk cw
  const int r0 = tid >> 3;
  const int c8 = tid & 7;
  const int cw = c8 ^ (r0 & 7);
  f32x4 alo[4], ahi[4];

  auto stageA = [&](int t) {  // full A tile via gload (4 ev)
#pragma unroll
    for (int h = 0; h < 2; ++h)
#pragma unroll
      for (int j = 0; j < 2; ++j) {
        int g = wid * 2 + j;
        gload16(Abf + (size_t)(bm + h * 128 + g * 8 + sgr) * K + t * BK + sgc * 8,
                &As[t & 1][h][g * 512]);
      }
  };
  auto stageB = [&](int t) {  // full B tile via gload (4 ev)
#pragma unroll
    for (int h = 0; h < 2; ++h)
#pragma unroll
      for (int j = 0; j < 2; ++j) {
        int g = wid * 2 + j;
        gload16(Bt + (size_t)(bn + h * 128 + g * 8 + sgr) * K + t * BK + sgc * 8,
                &Bs[t & 1][h][g * 512]);
      }
  };
  auto aload = [&](int t) {  // fp32 A tile -> regs (8 ev)
#pragma unroll
    for (int s = 0; s < 4; ++s) {
      const float* src = Af + (size_t)(bm + r0 + s * 64) * K + t * BK + c8 * 8;
      alo[s] = *(const f32x4*)src;
      ahi[s] = *(const f32x4*)(src + 4);
    }
  };
  auto awrite = [&](int t) {  // cvt + swizzled ds_write
#pragma unroll
    for (int s = 0; s < 4; ++s) {
      int row = r0 + s * 64;
      u16x8 o;
#pragma unroll
      for (int j = 0; j < 4; ++j) {
        o[j] = f2bf(alo[s][j]);
        o[4 + j] = f2bf(ahi[s][j]);
      }
      *(u16x8*)(&As[t & 1][row >> 7][(row & 127) * 64 + cw * 8]) = o;
    }
  };

  // ---- prologue: tile 0 only ----
  if (AF32) {
    aload(0);
    awrite(0);  // compiler inserts vmcnt wait for alo/ahi
  } else {
    stageA(0);
  }
  stageB(0);
  asm volatile("s_waitcnt vmcnt(0)" ::: "memory");
  asm volatile("s_waitcnt lgkmcnt(0)" ::: "memory");
  __builtin_amdgcn_s_barrier();
  MEMFENCE;

  bf16x8 bfr[4];
  for (int it = 0; it < nt / 2; ++it) {
    const int tA = 2 * it, tB = 2 * it + 1;
#pragma unroll
    for (int ph = 0; ph < 8; ++ph) {
      const int tsel = ph >> 2;     // 0: tA (dbuf0), 1: tB (dbuf1)
      const int kh = (ph >> 1) & 1;
      const int mh = ph & 1;
      // ---- ds-loads for this phase's MFMA ----
      if (mh == 0) {
#pragma unroll
        for (int nf = 0; nf < 4; ++nf) {
          int lr = (wc & 1) * 64 + nf * 16 + l15;
          int c7 = (kh * 4 + l4) ^ (lr & 7);
          bfr[nf] = *(const bf16x8*)(&Bs[tsel][wc >> 1][lr * 64 + c7 * 8]);
        }
      }
      bf16x8 af[4];
#pragma unroll
      for (int i = 0; i < 4; ++i) {
        int lr = (mh * 4 + i) * 16 + l15;
        int c7 = (kh * 4 + l4) ^ (lr & 7);
        af[i] = *(const bf16x8*)(&As[tsel][wr][lr * 64 + c7 * 8]);
      }
      // ---- staging duties (windows: dbuf1 @ ph0-2, dbuf0 @ ph4-6) ----
      if (ph == 0) {
        if (AF32) aload(tB); else stageA(tB);
      } else if (ph == 1) {
        stageB(tB);
      } else if (ph == 2) {
        if (AF32) awrite(tB);  // implicit vmcnt(4): aload aged 2 phases
      } else if (ph == 3) {
        asm volatile("s_waitcnt vmcnt(0)" ::: "memory");  // B(tB), aged 2
      } else if (ph == 4) {
        if (tA + 2 < nt) { if (AF32) aload(tA + 2); else stageA(tA + 2); }
      } else if (ph == 5) {
        if (tA + 2 < nt) stageB(tA + 2);
      } else if (ph == 6) {
        if (AF32 && tA + 2 < nt) awrite(tA + 2);
      } else {
        asm volatile("s_waitcnt vmcnt(0)" ::: "memory");  // B(tA+2), aged 2
      }
      MEMFENCE;
      __builtin_amdgcn_s_barrier();
      asm volatile("s_waitcnt lgkmcnt(0)" ::: "memory");
      __builtin_amdgcn_s_setprio(1);
#pragma unroll
      for (int i = 0; i < 4; ++i)
#pragma unroll
        for (int nf = 0; nf < 4; ++nf)
          acc[mh * 4 + i][nf] = __builtin_amdgcn_mfma_f32_16x16x32_bf16(
              af[i], bfr[nf], acc[mh * 4 + i][nf], 0, 0, 0);
      __builtin_amdgcn_s_setprio(0);
      MEMFENCE;
      __builtin_amdgcn_s_barrier();
      MEMFENCE;
    }
  }

  // ---- epilogue: bias, C write, optional fused scores ----
  // wave covers rows [bm+wr*128, +128), cols [bn+wc*64, +64) = head bx*4+wc
  const int crow = bm + wr * 128 + l4 * 4;
  const int ccol = bn + wc * 64 + l15;
  float pacc[8][4];
  if (SCORE) {
#pragma unroll
    for (int m = 0; m < 8; ++m)
#pragma unroll
      for (int e = 0; e < 4; ++e) pacc[m][e] = 0.f;
  }
  const float* wrow = nullptr;
  if (SCORE == 1) wrow = swt;
  if (SCORE == 2)
    wrow = swt + ((size_t)((bm >> 12) * HEADS + bx * 4 + wc)) * DKH;

#pragma unroll
  for (int m = 0; m < 8; ++m)
#pragma unroll
    for (int nf = 0; nf < 4; ++nf) {
      int c = ccol + nf * 16;
      float bj = bias[c];
      float wg = SCORE ? wrow[nf * 16 + l15] : 0.f;
#pragma unroll
      for (int e = 0; e < 4; ++e) {
        int r = crow + m * 16 + e;
        float v = acc[m][nf][e] + bj;
        if (SCORE) pacc[m][e] += v * wg;
        if (OBF)
          ((unsigned short*)C)[(size_t)r * N + c] = f2bf(v);
        else
          ((float*)C)[(size_t)r * N + c] = v;
      }
    }

  if (SCORE) {
#pragma unroll
    for (int m = 0; m < 8; ++m)
#pragma unroll
      for (int e = 0; e < 4; ++e) {
        float pv = pacc[m][e];
        pv += __shfl_xor(pv, 1);
        pv += __shfl_xor(pv, 2);
        pv += __shfl_xor(pv, 4);
        pv += __shfl_xor(pv, 8);
        if (l15 == 0) {
          int r = crow + m * 16 + e;
          int tt = r & (SEQ_T - 1), n = r >> 12;
          float sc = pv * 0.125f;
          if (mask[n * SEQ_T + tt] == 0) sc = -3.0e38f;
          sbuf[((size_t)n * HEADS + bx * 4 + wc) * SEQ_T + tt] = sc;
        }
      }
  }
}

// ---- per-chunk softmax partials: 1024 blocks = (nh, 16 chunks of 256) ----
__global__ void __launch_bounds__(256) k_stat1(const float* __restrict__ s,
                                               float* __restrict__ pmax,
                                               float* __restrict__ psum) {
  __shared__ float red[4];
  const int b = blockIdx.x, tid = threadIdx.x, lane = tid & 63, wid = tid >> 6;
  float v = s[(size_t)b * 256 + tid];
  float m = v;
#pragma unroll
  for (int o = 1; o < 64; o <<= 1) m = fmaxf(m, __shfl_xor(m, o));
  if (lane == 0) red[wid] = m;
  __syncthreads();
  m = fmaxf(fmaxf(red[0], red[1]), fmaxf(red[2], red[3]));
  __syncthreads();
  float e = __expf(v - m);
#pragma unroll
  for (int o = 1; o < 64; o <<= 1) e += __shfl_xor(e, o);
  if (lane == 0) red[wid] = e;
  __syncthreads();
  if (tid == 0) {
    pmax[b] = m;
    psum[b] = red[0] + red[1] + red[2] + red[3];
  }
}

// ---- combine 16 chunk partials -> per-(n,h) max & 1/sum ----
__global__ void __launch_bounds__(64) k_stat2(const float* __restrict__ pmax,
                                              const float* __restrict__ psum,
                                              float* __restrict__ smx,
                                              float* __restrict__ sinv) {
  const int b = blockIdx.x, lane = threadIdx.x;
  float pm = -3.4e38f, ps = 0.f;
  if (lane < 16) {
    pm = pmax[b * 16 + lane];
    ps = psum[b * 16 + lane];
  }
  float gm = pm;
#pragma unroll
  for (int o = 1; o < 16; o <<= 1) gm = fmaxf(gm, __shfl_xor(gm, o));
  float sc = ps * __expf(pm - gm);
#pragma unroll
  for (int o = 1; o < 16; o <<= 1) sc += __shfl_xor(sc, o);
  if (lane == 0) {
    smx[b] = gm;
    sinv[b] = 1.f / sc;
  }
}

// ---- chunked weighted sum: pbuf[nh,chunk,:] = sum_t w[t]*X[n,t,h,:] (bf16 X) ----
__global__ void __launch_bounds__(256) k_wsum(const unsigned short* __restrict__ X,
                                              const float* __restrict__ s,
                                              const float* __restrict__ mxv,
                                              const float* __restrict__ invv,
                                              float* __restrict__ pbuf) {
  __shared__ float part[16][64];
  const int nh = blockIdx.x >> 4, chunk = blockIdx.x & 15;
  const int n = nh >> 4, h = nh & 15;
  const int tid = threadIdx.x, lane = tid & 63, wid = tid >> 6;
  const int tsub = lane >> 4, dl = lane & 15;
  const float mx = mxv[nh], inv = invv[nh];
  const float* sb = s + (size_t)nh * SEQ_T + chunk * 256;
  const size_t base = ((size_t)n * SEQ_T + chunk * 256) * DMODEL + h * DKH + dl * 4;
  f32x4 acc = {0.f, 0.f, 0.f, 0.f};
  for (int t = wid * 4 + tsub; t < 256; t += 16) {
    float w = __expf(sb[t] - mx) * inv;
    u16x4 xv = *(const u16x4*)(X + base + (size_t)t * DMODEL);
    acc[0] += w * bf2f(xv[0]);
    acc[1] += w * bf2f(xv[1]);
    acc[2] += w * bf2f(xv[2]);
    acc[3] += w * bf2f(xv[3]);
  }
  int g = wid * 4 + tsub;
#pragma unroll
  for (int e = 0; e < 4; ++e) part[g][dl * 4 + e] = acc[e];
  __syncthreads();
  if (tid < 64) {
    float v = 0.f;
#pragma unroll
    for (int gg = 0; gg < 16; ++gg) v += part[gg][tid];
    pbuf[(size_t)blockIdx.x * 64 + tid] = v;
  }
}

// ---- final chunk reduce. MODE 0: out=gq, wv=gq*bw. MODE 1: out=gk=v*gq ----
template <int MODE>
__global__ void __launch_bounds__(64) k_fin(const float* __restrict__ pbuf,
                                            const float* __restrict__ gq,
                                            const float* __restrict__ bw,
                                            float* __restrict__ out,
                                            float* __restrict__ wv) {
  const int nh = blockIdx.x, d = threadIdx.x;
  float v = 0.f;
#pragma unroll
  for (int c = 0; c < 16; ++c) v += pbuf[((size_t)nh * 16 + c) * 64 + d];
  if (MODE == 1) v *= gq[(size_t)nh * 64 + d];
  out[(size_t)nh * 64 + d] = v;
  if (MODE == 0) wv[(size_t)nh * 64 + d] = v * bw[d];
}

// ---- WrgT[nh][d][dd] = gk[nh][dd] * Wr[dd][d]  (bf16) ----
__global__ void __launch_bounds__(256) k_wrg(const float* __restrict__ gk,
                                             const float* __restrict__ Wr,
                                             unsigned short* __restrict__ WrgT) {
  const int nh = blockIdx.x, tid = threadIdx.x;
#pragma unroll
  for (int i = 0; i < 16; ++i) {
    int idx = i * 256 + tid;
    int d = idx >> 6, dd = idx & 63;
    WrgT[(size_t)nh * 4096 + idx] = f2bf(gk[nh * 64 + dd] * Wr[dd * 64 + d]);
  }
}

// ---- A = v @ Wrg[nh] + br + q   (MFMA, one block = 128 rows x one head) ----
#define ABM 128
#define VLD 72  // padded LDS stride
__global__ void __launch_bounds__(256) k_abuild2(const unsigned short* __restrict__ v,
                                                 const unsigned short* __restrict__ qbf,
                                                 const unsigned short* __restrict__ WrgT,
                                                 const float* __restrict__ br,
                                                 unsigned short* __restrict__ A) {
  __shared__ unsigned short Vs[ABM * VLD];
  __shared__ unsigned short Ws[DKH * VLD];
  const int tid = threadIdx.x, lane = tid & 63, wid = tid >> 6;
  const int nh = blockIdx.y;
  const int n = nh >> 4, h = nh & 15;
  const size_t nt0 = (size_t)n * SEQ_T + (size_t)blockIdx.x * ABM;
  const size_t vbase = nt0 * DMODEL + (size_t)h * DKH;
#pragma unroll
  for (int p = 0; p < 4; ++p) {
    int idx = p * 256 + tid;
    int row = idx >> 3, c = idx & 7;
    *(u32x4*)(Vs + row * VLD + c * 8) =
        *(const u32x4*)(v + vbase + (size_t)row * DMODEL + c * 8);
  }
#pragma unroll
  for (int p = 0; p < 2; ++p) {
    int idx = p * 256 + tid;
    int row = idx >> 3, c = idx & 7;
    *(u32x4*)(Ws + row * VLD + c * 8) =
        *(const u32x4*)(WrgT + (size_t)nh * 4096 + row * 64 + c * 8);
  }
  __syncthreads();
  const int l15 = lane & 15, l4 = lane >> 4;
  f32x4 acc[2][4];
#pragma unroll
  for (int m = 0; m < 2; ++m)
#pragma unroll
    for (int nf = 0; nf < 4; ++nf)
#pragma unroll
      for (int e = 0; e < 4; ++e) acc[m][nf][e] = 0.f;
#pragma unroll
  for (int ks = 0; ks < 2; ++ks) {
    bf16x8 af[2], bfr[4];
#pragma unroll
    for (int m = 0; m < 2; ++m)
      af[m] = *(const bf16x8*)(Vs + (wid * 32 + m * 16 + l15) * VLD + l4 * 8 + ks * 32);
#pragma unroll
    for (int nf = 0; nf < 4; ++nf)
      bfr[nf] = *(const bf16x8*)(Ws + (nf * 16 + l15) * VLD + l4 * 8 + ks * 32);
#pragma unroll
    for (int m = 0; m < 2; ++m)
#pragma unroll
      for (int nf = 0; nf < 4; ++nf)
        acc[m][nf] = __builtin_amdgcn_mfma_f32_16x16x32_bf16(af[m], bfr[nf],
                                                             acc[m][nf], 0, 0, 0);
  }
#pragma unroll
  for (int m = 0; m < 2; ++m)
#pragma unroll
    for (int nf = 0; nf < 4; ++nf) {
      int d = nf * 16 + l15;
      float bj = br[d];
#pragma unroll
      for (int e = 0; e < 4; ++e) {
        int r = wid * 32 + m * 16 + l4 * 4 + e;
        size_t off = vbase + (size_t)r * DMODEL + d;
        float val = acc[m][nf][e] + bj + bf2f(qbf[off]);
        A[off] = f2bf(val);
      }
    }
}

extern "C" void kernel_launch(void* const* d_in, const int* in_sizes, int n_in,
                              void* d_out, int out_size, void* d_ws, size_t ws_size,
                              hipStream_t stream) {
  const float* x_k = (const float*)d_in[0];
  const float* x_v = (const float*)d_in[1];
  const float* x_q = (const float*)d_in[2];
  const int* mask = (const int*)d_in[3];
  const float* Wk = (const float*)d_in[4];
  const float* bk = (const float*)d_in[5];
  const float* Wv = (const float*)d_in[6];
  const float* bv = (const float*)d_in[7];
  const float* Wq = (const float*)d_in[8];
  const float* bq = (const float*)d_in[9];
  const float* alpha_w = (const float*)d_in[10];
  const float* beta_w = (const float*)d_in[11];
  const float* Wr = (const float*)d_in[12];
  const float* br = (const float*)d_in[13];
  const float* Wfc = (const float*)d_in[14];
  const float* bfc = (const float*)d_in[15];

  // q (bf16) lives in d_out's first 32MB; dead before final GEMM overwrites.
  unsigned short* qbf = (unsigned short*)d_out;

  char* ws = (char*)d_ws;
  const size_t SZ_XBF = (size_t)MTOK * DMODEL * 2;  // 32 MiB
  unsigned short* kbf = (unsigned short*)(ws);
  unsigned short* vbf = (unsigned short*)(ws + SZ_XBF);
  unsigned short* xst = (unsigned short*)(ws + 2 * SZ_XBF);  // A matrix
  unsigned short* WkT = (unsigned short*)(ws + 3 * SZ_XBF);
  unsigned short* WvT = WkT + (size_t)DMODEL * DMODEL;
  unsigned short* WqT = WvT + (size_t)DMODEL * DMODEL;
  unsigned short* WfT = WqT + (size_t)DMODEL * DMODEL;
  unsigned short* WrgT = WfT + (size_t)DMODEL * DMODEL;     // 64*4096 bf16
  float* gq = (float*)(WrgT + (size_t)64 * 4096);
  float* gk = gq + 4096;
  float* wvb = gk + 4096;
  float* sbuf = wvb + 4096;                  // 64*4096 fp32 = 1 MiB
  float* pbuf = sbuf + (size_t)64 * SEQ_T;   // 1024*64 fp32
  float* pmax = pbuf + 1024 * 64;
  float* psum = pmax + 1024;
  float* smx = psum + 1024;
  float* sinv = smx + 64;

  dim3 tb(32, 8);
  dim3 tg(DMODEL / 32, DMODEL / 32);
  k_wtrans<<<tg, tb, 0, stream>>>(Wq, WqT, DMODEL, DMODEL);
  k_wtrans<<<tg, tb, 0, stream>>>(Wk, WkT, DMODEL, DMODEL);
  k_wtrans<<<tg, tb, 0, stream>>>(Wv, WvT, DMODEL, DMODEL);
  k_wtrans<<<tg, tb, 0, stream>>>(Wfc, WfT, DMODEL, DMODEL);

  dim3 ggrid(DMODEL / BN, MTOK / BM);  // (4, 64)

  // Q projection (fp32 A, fused alpha scores), q -> bf16
  k_gemm<1, 1, 1><<<ggrid, 512, 0, stream>>>(x_q, WqT, bq, (void*)qbf, mask,
                                             alpha_w, sbuf, MTOK, DMODEL, DMODEL);
  // alpha pooling
  k_stat1<<<1024, 256, 0, stream>>>(sbuf, pmax, psum);
  k_stat2<<<64, 64, 0, stream>>>(pmax, psum, smx, sinv);
  k_wsum<<<1024, 256, 0, stream>>>(qbf, sbuf, smx, sinv, pbuf);
  k_fin<0><<<64, 64, 0, stream>>>(pbuf, nullptr, beta_w, gq, wvb);

  // K projection (fp32 A, fused beta scores)
  k_gemm<1, 2, 1><<<ggrid, 512, 0, stream>>>(x_k, WkT, bk, (void*)kbf, mask,
                                             wvb, sbuf, MTOK, DMODEL, DMODEL);
  // beta pooling
  k_stat1<<<1024, 256, 0, stream>>>(sbuf, pmax, psum);
  k_stat2<<<64, 64, 0, stream>>>(pmax, psum, smx, sinv);
  k_wsum<<<1024, 256, 0, stream>>>(kbf, sbuf, smx, sinv, pbuf);
  k_fin<1><<<64, 64, 0, stream>>>(pbuf, gq, nullptr, gk, nullptr);

  // V projection (fp32 A)
  k_gemm<1, 0, 1><<<ggrid, 512, 0, stream>>>(x_v, WvT, bv, (void*)vbf, nullptr,
                                             nullptr, nullptr, MTOK, DMODEL, DMODEL);

  // A = v @ (diag(gk) Wr) + br + q
  k_wrg<<<64, 256, 0, stream>>>(gk, Wr, WrgT);
  dim3 agrid(SEQ_T / ABM, 64);
  k_abuild2<<<agrid, 256, 0, stream>>>(vbf, qbf, WrgT, br, xst);

  // final projection (bf16 A)
  k_gemm<0, 0, 0><<<ggrid, 512, 0, stream>>>(xst, WfT, bfc, d_out, nullptr,
                                             nullptr, nullptr, MTOK, DMODEL, DMODEL);
}

// Round 7
// 331.345 us; speedup vs baseline: 1.1127x; 1.1127x over previous
//
#include <hip/hip_runtime.h>

typedef __bf16 bf16x8 __attribute__((ext_vector_type(8)));
typedef float f32x4 __attribute__((ext_vector_type(4)));
typedef unsigned int u32x4 __attribute__((ext_vector_type(4)));
typedef unsigned short u16x4 __attribute__((ext_vector_type(4)));
typedef unsigned short u16x8 __attribute__((ext_vector_type(8)));

#define SEQ_T 4096
#define DMODEL 1024
#define HEADS 16
#define DKH 64
#define MTOK 16384  // N*T rows

#define AS1 __attribute__((address_space(1)))
#define AS3 __attribute__((address_space(3)))
#define MEMFENCE asm volatile("" ::: "memory")

__device__ __forceinline__ unsigned short f2bf(float f) {
  unsigned u = __builtin_bit_cast(unsigned int, f);
  u += 0x7FFFu + ((u >> 16) & 1u);
  return (unsigned short)(u >> 16);
}
__device__ __forceinline__ float bf2f(unsigned short h) {
  unsigned u = ((unsigned)h) << 16;
  return __builtin_bit_cast(float, u);
}
__device__ __forceinline__ void gload16(const unsigned short* g, unsigned short* l) {
  __builtin_amdgcn_global_load_lds((const AS1 unsigned int*)(g),
                                   (AS3 unsigned int*)(l), 16, 0, 0);
}

// ---------------- W (K x N) fp32 -> Wt (N x K) bf16 ----------------
__global__ void __launch_bounds__(256) k_wtrans(const float* __restrict__ W,
                                                unsigned short* __restrict__ Wt,
                                                int K, int N) {
  __shared__ float tile[32][33];
  int bn = blockIdx.x * 32, bk = blockIdx.y * 32;
  int tx = threadIdx.x, ty = threadIdx.y;  // 32 x 8
#pragma unroll
  for (int j = 0; j < 32; j += 8)
    tile[ty + j][tx] = W[(size_t)(bk + ty + j) * N + bn + tx];
  __syncthreads();
#pragma unroll
  for (int j = 0; j < 32; j += 8)
    Wt[(size_t)(bn + ty + j) * K + bk + tx] = f2bf(tile[tx][ty + j]);
}

// ====== 128x128 bf16 NT GEMM (m97 2-barrier structure), BK=64, 4 waves ======
// C = A(MxK)*Bt(NxK)^T + bias.  AF32: A fp32, converted during reg-staging
// (fuses the f32->bf16 pass).  B staged via global_load_lds with pre-swizzled
// source (chunk ^= row&7); A (AF32) reg-staged with swizzled ds_write; all
// ds_reads use the matching XOR -> ~0 bank conflicts (round-4 validated).
// aload(t+1) issued after the frag reads so its drain (next iter's barrier)
// ages across the MFMA phase.  SCORE=1/2: fused alpha/beta score epilogue.
#define BM 128
#define BN 128
#define BK 64

template <int OBF, int SCORE, int AF32>
__global__ void __launch_bounds__(256, 2)
k_gemm(const void* __restrict__ Ain, const unsigned short* __restrict__ Bt,
       const float* __restrict__ bias, void* __restrict__ C,
       const int* __restrict__ mask, const float* __restrict__ swt,
       float* __restrict__ sbuf, int M, int N, int K) {
  __shared__ unsigned short As[BM * BK];
  __shared__ unsigned short Bs[BN * BK];
  const int tid = threadIdx.x;
  const int lane = tid & 63, wid = tid >> 6;
  const int wr = wid >> 1, wc = wid & 1;  // 2x2 waves, 64x64 C each
  const int l15 = lane & 15, l4 = lane >> 4;

  // bijective XCD-chunked swizzle (nwg = 8*128 = 1024, %8 == 0)
  const int nwg = gridDim.x * gridDim.y;
  const int flat = blockIdx.x + blockIdx.y * gridDim.x;
  const int rm = (flat & 7) * (nwg >> 3) + (flat >> 3);
  const int bx = rm % gridDim.x, by = rm / gridDim.x;
  const int bm = by * BM, bn = bx * BN;

  const float* Af = (const float*)Ain;
  const unsigned short* Abf = (const unsigned short*)Ain;
  const int nt = K / BK;

  f32x4 acc[4][4];
#pragma unroll
  for (int i = 0; i < 4; ++i)
#pragma unroll
    for (int j = 0; j < 4; ++j)
#pragma unroll
      for (int e = 0; e < 4; ++e) acc[i][j][e] = 0.f;

  // gload staging: group g = 8 rows; lane -> row +(l>>3), src chunk
  // (l&7)^(l>>3) = chunk^(row&7); LDS dest linear.
  const int sgr = lane >> 3;
  const int sgc = (lane & 7) ^ sgr;
  // AF32 reg staging: slots s=0,1 -> row r0+s*64; colgroup c4 = 16 floats.
  const int r0 = tid >> 2;
  const int c4 = tid & 3;
  f32x4 alv[2][4];

  auto stageB = [&](int t) {  // 4 instrs/wave
#pragma unroll
    for (int j = 0; j < 4; ++j) {
      int g = wid * 4 + j;
      gload16(Bt + (size_t)(bn + g * 8 + sgr) * K + t * BK + sgc * 8,
              Bs + g * 512);
    }
  };
  auto stageAbf = [&](int t) {
#pragma unroll
    for (int j = 0; j < 4; ++j) {
      int g = wid * 4 + j;
      gload16(Abf + (size_t)(bm + g * 8 + sgr) * K + t * BK + sgc * 8,
              As + g * 512);
    }
  };
  auto aload = [&](int t) {  // 8 vm loads into regs
#pragma unroll
    for (int s = 0; s < 2; ++s) {
      const float* src = Af + (size_t)(bm + r0 + s * 64) * K + t * BK + c4 * 16;
#pragma unroll
      for (int j = 0; j < 4; ++j) alv[s][j] = *(const f32x4*)(src + j * 4);
    }
  };
  auto awrite = [&]() {  // cvt + swizzled ds_write (2 x 16B per slot)
#pragma unroll
    for (int s = 0; s < 2; ++s) {
      int row = r0 + s * 64;
#pragma unroll
      for (int half = 0; half < 2; ++half) {
        u16x8 o;
#pragma unroll
        for (int j = 0; j < 8; ++j) o[j] = f2bf(alv[s][half * 2 + (j >> 2)][j & 3]);
        int ch = (c4 * 2 + half) ^ (row & 7);
        *(u16x8*)(As + row * BK + ch * 8) = o;
      }
    }
  };

  if (AF32) aload(0);

  for (int t = 0; t < nt; ++t) {
    __syncthreads();  // previous tile consumed (drains aload(t) too, aged)
    if (AF32) awrite();
    else stageAbf(t);
    stageB(t);
    __syncthreads();  // vmcnt+lgkm drained -> tile resident
#pragma unroll
    for (int kh = 0; kh < 2; ++kh) {
      bf16x8 af[4], bfr[4];
#pragma unroll
      for (int m = 0; m < 4; ++m) {
        int ra = wr * 64 + m * 16 + l15;
        int c7 = (kh * 4 + l4) ^ (ra & 7);
        af[m] = *(const bf16x8*)(As + ra * BK + c7 * 8);
      }
#pragma unroll
      for (int n = 0; n < 4; ++n) {
        int rb = wc * 64 + n * 16 + l15;
        int c7 = (kh * 4 + l4) ^ (rb & 7);
        bfr[n] = *(const bf16x8*)(Bs + rb * BK + c7 * 8);
      }
      if (AF32 && kh == 0 && t + 1 < nt) aload(t + 1);  // overlaps MFMA
#pragma unroll
      for (int m = 0; m < 4; ++m)
#pragma unroll
        for (int n = 0; n < 4; ++n)
          acc[m][n] = __builtin_amdgcn_mfma_f32_16x16x32_bf16(af[m], bfr[n],
                                                              acc[m][n], 0, 0, 0);
    }
  }

  // ---- epilogue: bias, C write, optional fused scores ----
  const int crow = bm + wr * 64 + l4 * 4;
  const int ccol = bn + wc * 64 + l15;
  float pacc[4][4];
  const float* wrow = nullptr;
  if (SCORE == 1) wrow = swt;
  if (SCORE == 2) wrow = swt + ((size_t)((bm >> 12) * HEADS + bx * 2 + wc)) * DKH;
  if (SCORE) {
#pragma unroll
    for (int m = 0; m < 4; ++m)
#pragma unroll
      for (int e = 0; e < 4; ++e) pacc[m][e] = 0.f;
  }

#pragma unroll
  for (int m = 0; m < 4; ++m)
#pragma unroll
    for (int n = 0; n < 4; ++n) {
      int c = ccol + n * 16;
      float bj = bias[c];
      float wg = SCORE ? wrow[n * 16 + l15] : 0.f;
#pragma unroll
      for (int e = 0; e < 4; ++e) {
        int r = crow + m * 16 + e;
        float v = acc[m][n][e] + bj;
        if (SCORE) pacc[m][e] += v * wg;
        if (OBF)
          ((unsigned short*)C)[(size_t)r * N + c] = f2bf(v);
        else
          ((float*)C)[(size_t)r * N + c] = v;
      }
    }

  if (SCORE) {
#pragma unroll
    for (int m = 0; m < 4; ++m)
#pragma unroll
      for (int e = 0; e < 4; ++e) {
        float p = pacc[m][e];
        p += __shfl_xor(p, 1);
        p += __shfl_xor(p, 2);
        p += __shfl_xor(p, 4);
        p += __shfl_xor(p, 8);
        if (l15 == 0) {
          int r = crow + m * 16 + e;
          int tt = r & (SEQ_T - 1), n = r >> 12;
          float sc = p * 0.125f;
          if (mask[n * SEQ_T + tt] == 0) sc = -3.0e38f;
          sbuf[((size_t)n * HEADS + bx * 2 + wc) * SEQ_T + tt] = sc;
        }
      }
  }
}

// ---- per-chunk softmax partials: 1024 blocks = (nh, 16 chunks of 256) ----
__global__ void __launch_bounds__(256) k_stat1(const float* __restrict__ s,
                                               float* __restrict__ pmax,
                                               float* __restrict__ psum) {
  __shared__ float red[4];
  const int b = blockIdx.x, tid = threadIdx.x, lane = tid & 63, wid = tid >> 6;
  float v = s[(size_t)b * 256 + tid];
  float m = v;
#pragma unroll
  for (int o = 1; o < 64; o <<= 1) m = fmaxf(m, __shfl_xor(m, o));
  if (lane == 0) red[wid] = m;
  __syncthreads();
  m = fmaxf(fmaxf(red[0], red[1]), fmaxf(red[2], red[3]));
  __syncthreads();
  float e = __expf(v - m);
#pragma unroll
  for (int o = 1; o < 64; o <<= 1) e += __shfl_xor(e, o);
  if (lane == 0) red[wid] = e;
  __syncthreads();
  if (tid == 0) {
    pmax[b] = m;
    psum[b] = red[0] + red[1] + red[2] + red[3];
  }
}

// ---- combine 16 chunk partials -> per-(n,h) max & 1/sum ----
__global__ void __launch_bounds__(64) k_stat2(const float* __restrict__ pmax,
                                              const float* __restrict__ psum,
                                              float* __restrict__ smx,
                                              float* __restrict__ sinv) {
  const int b = blockIdx.x, lane = threadIdx.x;
  float pm = -3.4e38f, ps = 0.f;
  if (lane < 16) {
    pm = pmax[b * 16 + lane];
    ps = psum[b * 16 + lane];
  }
  float gm = pm;
#pragma unroll
  for (int o = 1; o < 16; o <<= 1) gm = fmaxf(gm, __shfl_xor(gm, o));
  float sc = ps * __expf(pm - gm);
#pragma unroll
  for (int o = 1; o < 16; o <<= 1) sc += __shfl_xor(sc, o);
  if (lane == 0) {
    smx[b] = gm;
    sinv[b] = 1.f / sc;
  }
}

// ---- chunked weighted sum: pbuf[nh,chunk,:] = sum_t w[t]*X[n,t,h,:] (bf16 X) ----
__global__ void __launch_bounds__(256) k_wsum(const unsigned short* __restrict__ X,
                                              const float* __restrict__ s,
                                              const float* __restrict__ mxv,
                                              const float* __restrict__ invv,
                                              float* __restrict__ pbuf) {
  __shared__ float part[16][64];
  const int nh = blockIdx.x >> 4, chunk = blockIdx.x & 15;
  const int n = nh >> 4, h = nh & 15;
  const int tid = threadIdx.x, lane = tid & 63, wid = tid >> 6;
  const int tsub = lane >> 4, dl = lane & 15;
  const float mx = mxv[nh], inv = invv[nh];
  const float* sb = s + (size_t)nh * SEQ_T + chunk * 256;
  const size_t base = ((size_t)n * SEQ_T + chunk * 256) * DMODEL + h * DKH + dl * 4;
  f32x4 acc = {0.f, 0.f, 0.f, 0.f};
  for (int t = wid * 4 + tsub; t < 256; t += 16) {
    float w = __expf(sb[t] - mx) * inv;
    u16x4 xv = *(const u16x4*)(X + base + (size_t)t * DMODEL);
    acc[0] += w * bf2f(xv[0]);
    acc[1] += w * bf2f(xv[1]);
    acc[2] += w * bf2f(xv[2]);
    acc[3] += w * bf2f(xv[3]);
  }
  int g = wid * 4 + tsub;
#pragma unroll
  for (int e = 0; e < 4; ++e) part[g][dl * 4 + e] = acc[e];
  __syncthreads();
  if (tid < 64) {
    float v = 0.f;
#pragma unroll
    for (int gg = 0; gg < 16; ++gg) v += part[gg][tid];
    pbuf[(size_t)blockIdx.x * 64 + tid] = v;
  }
}

// ---- final chunk reduce. MODE 0: out=gq, wv=gq*bw. MODE 1: out=gk=v*gq ----
template <int MODE>
__global__ void __launch_bounds__(64) k_fin(const float* __restrict__ pbuf,
                                            const float* __restrict__ gq,
                                            const float* __restrict__ bw,
                                            float* __restrict__ out,
                                            float* __restrict__ wv) {
  const int nh = blockIdx.x, d = threadIdx.x;
  float v = 0.f;
#pragma unroll
  for (int c = 0; c < 16; ++c) v += pbuf[((size_t)nh * 16 + c) * 64 + d];
  if (MODE == 1) v *= gq[(size_t)nh * 64 + d];
  out[(size_t)nh * 64 + d] = v;
  if (MODE == 0) wv[(size_t)nh * 64 + d] = v * bw[d];
}

// ---- WrgT[nh][d][dd] = gk[nh][dd] * Wr[dd][d]  (bf16) ----
__global__ void __launch_bounds__(256) k_wrg(const float* __restrict__ gk,
                                             const float* __restrict__ Wr,
                                             unsigned short* __restrict__ WrgT) {
  const int nh = blockIdx.x, tid = threadIdx.x;
#pragma unroll
  for (int i = 0; i < 16; ++i) {
    int idx = i * 256 + tid;
    int d = idx >> 6, dd = idx & 63;
    WrgT[(size_t)nh * 4096 + idx] = f2bf(gk[nh * 64 + dd] * Wr[dd * 64 + d]);
  }
}

// ---- A = v @ Wrg[nh] + br + q   (MFMA, one block = 128 rows x one head) ----
#define ABM 128
#define VLD 72  // padded LDS stride
__global__ void __launch_bounds__(256) k_abuild2(const unsigned short* __restrict__ v,
                                                 const unsigned short* __restrict__ qbf,
                                                 const unsigned short* __restrict__ WrgT,
                                                 const float* __restrict__ br,
                                                 unsigned short* __restrict__ A) {
  __shared__ unsigned short Vs[ABM * VLD];
  __shared__ unsigned short Ws[DKH * VLD];
  const int tid = threadIdx.x, lane = tid & 63, wid = tid >> 6;
  const int nh = blockIdx.y;
  const int n = nh >> 4, h = nh & 15;
  const size_t nt0 = (size_t)n * SEQ_T + (size_t)blockIdx.x * ABM;
  const size_t vbase = nt0 * DMODEL + (size_t)h * DKH;
#pragma unroll
  for (int p = 0; p < 4; ++p) {
    int idx = p * 256 + tid;
    int row = idx >> 3, c = idx & 7;
    *(u32x4*)(Vs + row * VLD + c * 8) =
        *(const u32x4*)(v + vbase + (size_t)row * DMODEL + c * 8);
  }
#pragma unroll
  for (int p = 0; p < 2; ++p) {
    int idx = p * 256 + tid;
    int row = idx >> 3, c = idx & 7;
    *(u32x4*)(Ws + row * VLD + c * 8) =
        *(const u32x4*)(WrgT + (size_t)nh * 4096 + row * 64 + c * 8);
  }
  __syncthreads();
  const int l15 = lane & 15, l4 = lane >> 4;
  f32x4 acc[2][4];
#pragma unroll
  for (int m = 0; m < 2; ++m)
#pragma unroll
    for (int nf = 0; nf < 4; ++nf)
#pragma unroll
      for (int e = 0; e < 4; ++e) acc[m][nf][e] = 0.f;
#pragma unroll
  for (int ks = 0; ks < 2; ++ks) {
    bf16x8 af[2], bfr[4];
#pragma unroll
    for (int m = 0; m < 2; ++m)
      af[m] = *(const bf16x8*)(Vs + (wid * 32 + m * 16 + l15) * VLD + l4 * 8 + ks * 32);
#pragma unroll
    for (int nf = 0; nf < 4; ++nf)
      bfr[nf] = *(const bf16x8*)(Ws + (nf * 16 + l15) * VLD + l4 * 8 + ks * 32);
#pragma unroll
    for (int m = 0; m < 2; ++m)
#pragma unroll
      for (int nf = 0; nf < 4; ++nf)
        acc[m][nf] = __builtin_amdgcn_mfma_f32_16x16x32_bf16(af[m], bfr[nf],
                                                             acc[m][nf], 0, 0, 0);
  }
#pragma unroll
  for (int m = 0; m < 2; ++m)
#pragma unroll
    for (int nf = 0; nf < 4; ++nf) {
      int d = nf * 16 + l15;
      float bj = br[d];
#pragma unroll
      for (int e = 0; e < 4; ++e) {
        int r = wid * 32 + m * 16 + l4 * 4 + e;
        size_t off = vbase + (size_t)r * DMODEL + d;
        float val = acc[m][nf][e] + bj + bf2f(qbf[off]);
        A[off] = f2bf(val);
      }
    }
}

extern "C" void kernel_launch(void* const* d_in, const int* in_sizes, int n_in,
                              void* d_out, int out_size, void* d_ws, size_t ws_size,
                              hipStream_t stream) {
  const float* x_k = (const float*)d_in[0];
  const float* x_v = (const float*)d_in[1];
  const float* x_q = (const float*)d_in[2];
  const int* mask = (const int*)d_in[3];
  const float* Wk = (const float*)d_in[4];
  const float* bk = (const float*)d_in[5];
  const float* Wv = (const float*)d_in[6];
  const float* bv = (const float*)d_in[7];
  const float* Wq = (const float*)d_in[8];
  const float* bq = (const float*)d_in[9];
  const float* alpha_w = (const float*)d_in[10];
  const float* beta_w = (const float*)d_in[11];
  const float* Wr = (const float*)d_in[12];
  const float* br = (const float*)d_in[13];
  const float* Wfc = (const float*)d_in[14];
  const float* bfc = (const float*)d_in[15];

  // q (bf16) lives in d_out's first 32MB; dead before final GEMM overwrites.
  unsigned short* qbf = (unsigned short*)d_out;

  char* ws = (char*)d_ws;
  const size_t SZ_XBF = (size_t)MTOK * DMODEL * 2;  // 32 MiB
  unsigned short* kbf = (unsigned short*)(ws);
  unsigned short* vbf = (unsigned short*)(ws + SZ_XBF);
  unsigned short* xst = (unsigned short*)(ws + 2 * SZ_XBF);  // A matrix
  unsigned short* WkT = (unsigned short*)(ws + 3 * SZ_XBF);
  unsigned short* WvT = WkT + (size_t)DMODEL * DMODEL;
  unsigned short* WqT = WvT + (size_t)DMODEL * DMODEL;
  unsigned short* WfT = WqT + (size_t)DMODEL * DMODEL;
  unsigned short* WrgT = WfT + (size_t)DMODEL * DMODEL;     // 64*4096 bf16
  float* gq = (float*)(WrgT + (size_t)64 * 4096);
  float* gk = gq + 4096;
  float* wvb = gk + 4096;
  float* sbuf = wvb + 4096;                  // 64*4096 fp32 = 1 MiB
  float* pbuf = sbuf + (size_t)64 * SEQ_T;   // 1024*64 fp32
  float* pmax = pbuf + 1024 * 64;
  float* psum = pmax + 1024;
  float* smx = psum + 1024;
  float* sinv = smx + 64;

  dim3 tb(32, 8);
  dim3 tg(DMODEL / 32, DMODEL / 32);
  k_wtrans<<<tg, tb, 0, stream>>>(Wq, WqT, DMODEL, DMODEL);
  k_wtrans<<<tg, tb, 0, stream>>>(Wk, WkT, DMODEL, DMODEL);
  k_wtrans<<<tg, tb, 0, stream>>>(Wv, WvT, DMODEL, DMODEL);
  k_wtrans<<<tg, tb, 0, stream>>>(Wfc, WfT, DMODEL, DMODEL);

  dim3 ggrid(DMODEL / BN, MTOK / BM);  // (8, 128) = 1024 blocks

  // Q projection (fp32 A, fused alpha scores), q -> bf16
  k_gemm<1, 1, 1><<<ggrid, 256, 0, stream>>>(x_q, WqT, bq, (void*)qbf, mask,
                                             alpha_w, sbuf, MTOK, DMODEL, DMODEL);
  // alpha pooling
  k_stat1<<<1024, 256, 0, stream>>>(sbuf, pmax, psum);
  k_stat2<<<64, 64, 0, stream>>>(pmax, psum, smx, sinv);
  k_wsum<<<1024, 256, 0, stream>>>(qbf, sbuf, smx, sinv, pbuf);
  k_fin<0><<<64, 64, 0, stream>>>(pbuf, nullptr, beta_w, gq, wvb);

  // K projection (fp32 A, fused beta scores)
  k_gemm<1, 2, 1><<<ggrid, 256, 0, stream>>>(x_k, WkT, bk, (void*)kbf, mask,
                                             wvb, sbuf, MTOK, DMODEL, DMODEL);
  // beta pooling
  k_stat1<<<1024, 256, 0, stream>>>(sbuf, pmax, psum);
  k_stat2<<<64, 64, 0, stream>>>(pmax, psum, smx, sinv);
  k_wsum<<<1024, 256, 0, stream>>>(kbf, sbuf, smx, sinv, pbuf);
  k_fin<1><<<64, 64, 0, stream>>>(pbuf, gq, nullptr, gk, nullptr);

  // V projection (fp32 A)
  k_gemm<1, 0, 1><<<ggrid, 256, 0, stream>>>(x_v, WvT, bv, (void*)vbf, nullptr,
                                             nullptr, nullptr, MTOK, DMODEL, DMODEL);

  // A = v @ (diag(gk) Wr) + br + q
  k_wrg<<<64, 256, 0, stream>>>(gk, Wr, WrgT);
  dim3 agrid(SEQ_T / ABM, 64);
  k_abuild2<<<agrid, 256, 0, stream>>>(vbf, qbf, WrgT, br, xst);

  // final projection (bf16 A)
  k_gemm<0, 0, 0><<<ggrid, 256, 0, stream>>>(xst, WfT, bfc, d_out, nullptr,
                                             nullptr, nullptr, MTOK, DMODEL, DMODEL);
}